// Round 6
// baseline (135.435 us; speedup 1.0000x reference)
//
#include <hip/hip_runtime.h>
#include <math.h>

typedef float f32x4 __attribute__((ext_vector_type(4)));

#define BLOCK 256
#define GRID  512     // 2 blocks/CU resident (VGPR-capped), single dispatch wave

// Inline-asm global load: untracked by compiler waitcnt insertion, so our
// counted vmcnt governs. Immediate offset keeps one addr pair per array.
#define GLOADO(dst, base, OFF) \
  asm volatile("global_load_dwordx4 %0, %1, off offset:" #OFF : "=v"(dst) : "v"(base))

#define WAITV(n) asm volatile("s_waitcnt vmcnt(" #n ")" ::: "memory")

__global__ __launch_bounds__(BLOCK, 2) void rmse_partial_kernel(
    const float* __restrict__ rot_kf, const float* __restrict__ pose_kf,
    const float* __restrict__ rot_gt, const float* __restrict__ pose_gt,
    float* __restrict__ partial, int N)
{
    __shared__ float redbuf[BLOCK / 64];

    const int tid0 = blockIdx.x * BLOCK + threadIdx.x;
    const int T = gridDim.x * BLOCK;
    const int G = (N + 3) >> 2;              // 4-frame groups
    const int kmax = (G + T - 1) / T;        // grid-uniform trip count

    // two register banks: 48 f32x4 = 192 VGPRs held
    f32x4 A0[9], B0[9], K0[3], P0[3];
    f32x4 A1[9], B1[9], K1[3], P1[3];

    float sum = 0.0f;

    // issue one group's 24 loads (9+9+3+3), back-to-back, immediate offsets
    auto issueAll = [&](f32x4* Ar, f32x4* Br, f32x4* Kr, f32x4* Pr, int g) {
        const char* ra = (const char*)rot_kf  + (size_t)g * 144u;
        const char* rb = (const char*)rot_gt  + (size_t)g * 144u;
        const char* ka = (const char*)pose_kf + (size_t)g * 48u;
        const char* pg = (const char*)pose_gt + (size_t)g * 48u;
        GLOADO(Ar[0], ra, 0);   GLOADO(Ar[1], ra, 16);  GLOADO(Ar[2], ra, 32);
        GLOADO(Ar[3], ra, 48);  GLOADO(Ar[4], ra, 64);  GLOADO(Ar[5], ra, 80);
        GLOADO(Ar[6], ra, 96);  GLOADO(Ar[7], ra, 112); GLOADO(Ar[8], ra, 128);
        GLOADO(Br[0], rb, 0);   GLOADO(Br[1], rb, 16);  GLOADO(Br[2], rb, 32);
        GLOADO(Br[3], rb, 48);  GLOADO(Br[4], rb, 64);  GLOADO(Br[5], rb, 80);
        GLOADO(Br[6], rb, 96);  GLOADO(Br[7], rb, 112); GLOADO(Br[8], rb, 128);
        GLOADO(Kr[0], ka, 0);   GLOADO(Kr[1], ka, 16);  GLOADO(Kr[2], ka, 32);
        GLOADO(Pr[0], pg, 0);   GLOADO(Pr[1], pg, 16);  GLOADO(Pr[2], pg, 32);
    };

    auto computeBank = [&](const f32x4* Ar, const f32x4* Br,
                           const f32x4* Kr, const f32x4* Pr, int g) {
        if (g >= G) return;
        const int f0 = g << 2;
        #pragma unroll
        for (int s = 0; s < 4; ++s) {
            if (f0 + s < N) {
                float a[9], b[9];
                #pragma unroll
                for (int i = 0; i < 9; ++i) {
                    const int e = s * 9 + i;         // constant after unroll
                    a[i] = Ar[e >> 2][e & 3];
                    b[i] = Br[e >> 2][e & 3];
                }
                const int e0 = s * 3, e1 = s * 3 + 1, e2 = s * 3 + 2;
                const float d0 = Pr[e0 >> 2][e0 & 3] - Kr[e0 >> 2][e0 & 3];
                const float d1 = Pr[e1 >> 2][e1 & 3] - Kr[e1 >> 2][e1 & 3];
                const float d2 = Pr[e2 >> 2][e2 & 3] - Kr[e2 >> 2][e2 & 3];
                float se = 0.0f;
                #pragma unroll
                for (int i = 0; i < 3; ++i) {
                    #pragma unroll
                    for (int k = 0; k < 3; ++k) {
                        // R_rel[i][k] = sum_j A[j][i]*B[j][k]  (row-major a[3j+i])
                        float r = a[i] * b[k] + a[3 + i] * b[3 + k] + a[6 + i] * b[6 + k];
                        r -= (i == k) ? 1.0f : 0.0f;
                        se += r * r;
                    }
                    const float t = a[i] * d0 + a[3 + i] * d1 + a[6 + i] * d2;
                    se += t * t;
                }
                sum += se;
            }
        }
    };

    int g = tid0;
    int k = 0;
    if (g < G) issueAll(A0, B0, K0, P0, g);

    while (k < kmax) {
        // ---- consume bank0(g), prefetch bank1(g+T) ----
        {
            const int gn = g + T;
            const bool anyNext = (k + 1 < kmax);
            const bool pf = anyNext && __any(gn < G);   // wave-uniform
            if (pf) {
                if (gn < G) issueAll(A1, B1, K1, P1, gn);
                WAITV(24);                               // bank0 landed, bank1 in flight
            } else {
                WAITV(0);
            }
            __builtin_amdgcn_sched_barrier(0);
            computeBank(A0, B0, K0, P0, g);
            if (!anyNext) { ++k; break; }
            ++k; g = gn;
        }
        // ---- consume bank1(g), prefetch bank0(g+T) ----
        {
            const int gn = g + T;
            const bool anyNext = (k + 1 < kmax);
            const bool pf = anyNext && __any(gn < G);
            if (pf) {
                if (gn < G) issueAll(A0, B0, K0, P0, gn);
                WAITV(24);
            } else {
                WAITV(0);
            }
            __builtin_amdgcn_sched_barrier(0);
            computeBank(A1, B1, K1, P1, g);
            if (!anyNext) { ++k; break; }
            ++k; g = gn;
        }
    }

    // ---- block reduction ----
    const int lane = threadIdx.x & 63;
    const int wave = threadIdx.x >> 6;
    #pragma unroll
    for (int off = 32; off > 0; off >>= 1) sum += __shfl_down(sum, off);
    if (lane == 0) redbuf[wave] = sum;
    __syncthreads();
    if (threadIdx.x == 0) {
        float s = 0.0f;
        #pragma unroll
        for (int w = 0; w < BLOCK / 64; ++w) s += redbuf[w];
        partial[blockIdx.x] = s;
    }
}

__global__ __launch_bounds__(256) void rmse_finalize_kernel(
    const float* __restrict__ partial, int nPartial, float* __restrict__ out, int N)
{
    __shared__ float redbuf[4];
    float sum = 0.0f;
    for (int i = threadIdx.x; i < nPartial; i += 256) sum += partial[i];
    #pragma unroll
    for (int off = 32; off > 0; off >>= 1) sum += __shfl_down(sum, off);
    const int lane = threadIdx.x & 63;
    const int wave = threadIdx.x >> 6;
    if (lane == 0) redbuf[wave] = sum;
    __syncthreads();
    if (threadIdx.x == 0) {
        float s = redbuf[0] + redbuf[1] + redbuf[2] + redbuf[3];
        out[0] = sqrtf(s / (float)N) + 1e-8f;
    }
}

extern "C" void kernel_launch(void* const* d_in, const int* in_sizes, int n_in,
                              void* d_out, int out_size, void* d_ws, size_t ws_size,
                              hipStream_t stream) {
    const float* rot_kf  = (const float*)d_in[0];
    const float* pose_kf = (const float*)d_in[1];
    const float* rot_gt  = (const float*)d_in[2];
    const float* pose_gt = (const float*)d_in[3];
    float* out = (float*)d_out;
    float* partial = (float*)d_ws;

    const int N = in_sizes[1] / 3;   // pose_kf is [N,3]
    const int G = (N + 3) >> 2;
    const int nBlocksNeeded = (G + BLOCK - 1) / BLOCK;

    int grid = GRID;
    if (grid > nBlocksNeeded) grid = nBlocksNeeded;
    const int wsCap = (int)(ws_size / sizeof(float));
    if (grid > wsCap) grid = wsCap;
    if (grid < 1) grid = 1;

    rmse_partial_kernel<<<grid, BLOCK, 0, stream>>>(rot_kf, pose_kf, rot_gt, pose_gt, partial, N);
    rmse_finalize_kernel<<<1, 256, 0, stream>>>(partial, grid, out, N);
}

// Round 7
// 69.248 us; speedup vs baseline: 1.9558x; 1.9558x over previous
//
#include <hip/hip_runtime.h>
#include <math.h>

#define BLOCK 256
#define FPC   256                 // frames per chunk, one frame per thread
#define F4M   (FPC * 9 / 4)       // 576 float4 per rot matrix per chunk
#define NBLOCKS 2048

__global__ __launch_bounds__(BLOCK, 8) void rmse_partial_kernel(
    const float* __restrict__ rot_kf, const float* __restrict__ pose_kf,
    const float* __restrict__ rot_gt, const float* __restrict__ pose_gt,
    float* __restrict__ partial, int N)
{
    // A and B staged together: 2 x 9216 B = 18432 B -> 8 blocks/CU
    __shared__ float ldsA[FPC * 9];
    __shared__ float ldsB[FPC * 9];
    __shared__ float redbuf[BLOCK / 64];

    const int tid = threadIdx.x;
    const long long totalF4 = (long long)N * 9 / 4;   // N*9 divisible by 4 when N%4==0
    const long long totalRotF = (long long)N * 9;
    const int nChunks = (int)(((long long)N + FPC - 1) / FPC);

    float sum = 0.0f;

    for (int c = blockIdx.x; c < nChunks; c += gridDim.x) {
        const long long base4 = (long long)c * F4M;

        __syncthreads();   // protect LDS reads of previous iteration

        // stage BOTH matrices' chunk (576 + 576 float4), then one barrier
        for (int i = tid; i < F4M; i += BLOCK) {
            const long long f4 = base4 + i;
            float4 v = make_float4(0.f, 0.f, 0.f, 0.f);
            if (f4 * 4 + 3 < totalRotF) v = reinterpret_cast<const float4*>(rot_kf)[f4];
            reinterpret_cast<float4*>(ldsA)[i] = v;
        }
        for (int i = tid; i < F4M; i += BLOCK) {
            const long long f4 = base4 + i;
            float4 v = make_float4(0.f, 0.f, 0.f, 0.f);
            if (f4 * 4 + 3 < totalRotF) v = reinterpret_cast<const float4*>(rot_gt)[f4];
            reinterpret_cast<float4*>(ldsB)[i] = v;
        }
        __syncthreads();

        const int f = c * FPC + tid;
        if (f < N) {
            float a[9], b[9];
            #pragma unroll
            for (int j = 0; j < 9; ++j) a[j] = ldsA[tid * 9 + j];
            #pragma unroll
            for (int j = 0; j < 9; ++j) b[j] = ldsB[tid * 9 + j];

            const long long p = (long long)f * 3;
            const float d0 = pose_gt[p + 0] - pose_kf[p + 0];
            const float d1 = pose_gt[p + 1] - pose_kf[p + 1];
            const float d2 = pose_gt[p + 2] - pose_kf[p + 2];

            float se = 0.0f;
            #pragma unroll
            for (int i = 0; i < 3; ++i) {
                #pragma unroll
                for (int k = 0; k < 3; ++k) {
                    // R_rel[i][k] = sum_j A[j][i] * B[j][k]
                    float r = a[i] * b[k] + a[3 + i] * b[3 + k] + a[6 + i] * b[6 + k];
                    r -= (i == k) ? 1.0f : 0.0f;
                    se += r * r;
                }
                const float t = a[i] * d0 + a[3 + i] * d1 + a[6 + i] * d2;
                se += t * t;
            }
            sum += se;
        }
    }

    // ---- block reduction ----
    const int lane = tid & 63;
    const int wave = tid >> 6;
    #pragma unroll
    for (int off = 32; off > 0; off >>= 1) sum += __shfl_down(sum, off);
    if (lane == 0) redbuf[wave] = sum;
    __syncthreads();
    if (tid == 0) {
        float s = 0.0f;
        #pragma unroll
        for (int w = 0; w < BLOCK / 64; ++w) s += redbuf[w];
        partial[blockIdx.x] = s;
    }
}

__global__ __launch_bounds__(BLOCK) void rmse_finalize_kernel(
    const float* __restrict__ partial, int nPartial, float* __restrict__ out, int N)
{
    __shared__ float redbuf[BLOCK / 64];
    float sum = 0.0f;
    for (int i = threadIdx.x; i < nPartial; i += BLOCK) sum += partial[i];
    #pragma unroll
    for (int off = 32; off > 0; off >>= 1) sum += __shfl_down(sum, off);
    const int lane = threadIdx.x & 63;
    const int wave = threadIdx.x >> 6;
    if (lane == 0) redbuf[wave] = sum;
    __syncthreads();
    if (threadIdx.x == 0) {
        float s = 0.0f;
        #pragma unroll
        for (int w = 0; w < BLOCK / 64; ++w) s += redbuf[w];
        out[0] = sqrtf(s / (float)N) + 1e-8f;
    }
}

extern "C" void kernel_launch(void* const* d_in, const int* in_sizes, int n_in,
                              void* d_out, int out_size, void* d_ws, size_t ws_size,
                              hipStream_t stream) {
    const float* rot_kf  = (const float*)d_in[0];
    const float* pose_kf = (const float*)d_in[1];
    const float* rot_gt  = (const float*)d_in[2];
    const float* pose_gt = (const float*)d_in[3];
    float* out = (float*)d_out;
    float* partial = (float*)d_ws;

    const int N = in_sizes[1] / 3;   // pose_kf is [N,3]
    const int nChunks = (int)(((long long)N + FPC - 1) / FPC);

    int grid = NBLOCKS;
    if (grid > nChunks) grid = nChunks;
    const int wsCap = (int)(ws_size / sizeof(float));
    if (grid > wsCap) grid = wsCap;
    if (grid < 1) grid = 1;

    rmse_partial_kernel<<<grid, BLOCK, 0, stream>>>(rot_kf, pose_kf, rot_gt, pose_gt, partial, N);
    rmse_finalize_kernel<<<1, BLOCK, 0, stream>>>(partial, grid, out, N);
}